// Round 2
// baseline (1111.956 us; speedup 1.0000x reference)
//
#include <hip/hip_runtime.h>
#include <stdint.h>

#define NN 50000
#define NE 800000
#define CH 128

// ---------------- threefry2x32 (exact JAX semantics) ----------------
__host__ __device__ inline void tf2x32(uint32_t k0, uint32_t k1, uint32_t& x0, uint32_t& x1) {
  uint32_t ks2 = k0 ^ k1 ^ 0x1BD11BDAu;
  x0 += k0; x1 += k1;
#define ROTL(v, r) (((v) << (r)) | ((v) >> (32 - (r))))
#define RND(r) { x0 += x1; x1 = ROTL(x1, r); x1 ^= x0; }
  RND(13) RND(15) RND(26) RND(6)
  x0 += k1; x1 += ks2 + 1u;
  RND(17) RND(29) RND(16) RND(24)
  x0 += ks2; x1 += k0 + 2u;
  RND(13) RND(15) RND(26) RND(6)
  x0 += k0; x1 += k1 + 3u;
  RND(17) RND(29) RND(16) RND(24)
  x0 += k1; x1 += ks2 + 4u;
  RND(13) RND(15) RND(26) RND(6)
  x0 += ks2; x1 += k0 + 5u;
#undef RND
#undef ROTL
}

__device__ inline float bits_to_u(uint32_t b) {
  float f = __uint_as_float(0x3F800000u | (b >> 9)) - 1.0f;  // [0,1)
  f = f + 1e-10f;                                             // *(max-min)+min, max-min==1.0f
  return fmaxf(1e-10f, f);
}

// ---------------- graph preprocessing ----------------
__global__ __launch_bounds__(256) void deg_k(const int* __restrict__ dst, int* __restrict__ degi) {
  int i = blockIdx.x * 256 + threadIdx.x;
  if (i < NE) atomicAdd(&degi[dst[i]], 1);
}

__global__ __launch_bounds__(256) void dinv_k(const int* __restrict__ degi, float* __restrict__ dinv) {
  int n = blockIdx.x * 256 + threadIdx.x;
  if (n < NN) {
    float d = (float)(degi[n] + 1);  // + self loop
    dinv[n] = 1.0f / sqrtf(d);       // XLA rewrites pow(x,-0.5) -> rsqrt
  }
}

__global__ __launch_bounds__(256) void scan1_k(const int* __restrict__ degi, int* __restrict__ offs,
                                               int* __restrict__ part) {
  __shared__ int tmp[256];
  int t = threadIdx.x, b = blockIdx.x, i = b * 256 + t;
  int v = (i < NN) ? degi[i] : 0;
  tmp[t] = v;
  __syncthreads();
  for (int s = 1; s < 256; s <<= 1) {
    int a = (t >= s) ? tmp[t - s] : 0;
    __syncthreads();
    tmp[t] += a;
    __syncthreads();
  }
  int incl = tmp[t];
  if (i < NN) offs[i] = incl - v;  // exclusive within chunk
  if (t == 255) part[b] = incl;
}

__global__ void scan2_k(int* part, int nparts) {
  if (threadIdx.x == 0 && blockIdx.x == 0) {
    int run = 0;
    for (int i = 0; i < nparts; ++i) { int v = part[i]; part[i] = run; run += v; }
  }
}

__global__ __launch_bounds__(256) void scan3_k(int* __restrict__ offs, const int* __restrict__ part) {
  int i = blockIdx.x * 256 + threadIdx.x;
  if (i < NN) offs[i] += part[blockIdx.x];
  if (i == 0) offs[NN] = NE;
}

__global__ __launch_bounds__(256) void place_k(const int* __restrict__ dst, const int* __restrict__ offs,
                                               int* __restrict__ cnt, int* __restrict__ eids) {
  int i = blockIdx.x * 256 + threadIdx.x;
  if (i < NE) {
    int d = dst[i];
    int p = offs[d] + atomicAdd(&cnt[d], 1);
    eids[p] = i;
  }
}

// deterministic intra-bucket order = ascending edge id (matches ref segment-sum order)
__global__ __launch_bounds__(256) void sort_k(const int* __restrict__ offs, int* __restrict__ eids) {
  int n = blockIdx.x * 256 + threadIdx.x;
  if (n >= NN) return;
  int s0 = offs[n], s1 = offs[n + 1];
  for (int i = s0 + 1; i < s1; ++i) {
    int v = eids[i];
    int j = i - 1;
    while (j >= s0 && eids[j] > v) { eids[j + 1] = eids[j]; --j; }
    eids[j + 1] = v;
  }
}

// ---------------- gumbel precompute ----------------
__global__ __launch_bounds__(256) void gum_k(float* __restrict__ gum,
                                             uint32_t k00, uint32_t k01, uint32_t k10, uint32_t k11,
                                             uint32_t k20, uint32_t k21) {
  int i = blockIdx.x * 256 + threadIdx.x;
  if (i >= 3 * NN) return;
  int l = i / NN;
  int n = i - l * NN;
  uint32_t kx, ky;
  if (l == 0) { kx = k00; ky = k01; }
  else if (l == 1) { kx = k10; ky = k11; }
  else { kx = k20; ky = k21; }
  // bits for element (n,c): flat index j=2n+c of a (50000,2) draw.
  // threefry counter-mode splits iota(100000) in halves: j<NN -> word0 of pair(j, j+NN);
  // j>=NN -> word1 of pair(j-NN, j).
  int j0 = 2 * n, j1 = 2 * n + 1;
  uint32_t w0, w1;
  if (j0 < NN) {
    uint32_t a0 = (uint32_t)j0, a1 = (uint32_t)(j0 + NN);
    tf2x32(kx, ky, a0, a1); w0 = a0;
    uint32_t b0 = (uint32_t)j1, b1 = (uint32_t)(j1 + NN);
    tf2x32(kx, ky, b0, b1); w1 = b0;
  } else {
    uint32_t a0 = (uint32_t)(j0 - NN), a1 = (uint32_t)j0;
    tf2x32(kx, ky, a0, a1); w0 = a1;
    uint32_t b0 = (uint32_t)(j1 - NN), b1 = (uint32_t)j1;
    tf2x32(kx, ky, b0, b1); w1 = b1;
  }
  float u0 = bits_to_u(w0), u1 = bits_to_u(w1);
  gum[2 * (size_t)i]     = -logf(-logf(u0));
  gum[2 * (size_t)i + 1] = -logf(-logf(u1));
}

// ---------------- h = x @ W  (f32, 32x128 tile, BK=32) ----------------
__global__ __launch_bounds__(256) void lin_k(const float* __restrict__ x, const float* __restrict__ W,
                                             float* __restrict__ h) {
  __shared__ float Ws[32 * 128];
  __shared__ float xs[32 * 32];
  int t = threadIdx.x;
  int row0 = blockIdx.x << 5;
  int c4 = t & 31;   // float4 column group (cols 4*c4 .. 4*c4+3)
  int ty = t >> 5;   // 0..7 -> rows ty, ty+8, ty+16, ty+24
  float4 acc[4];
#pragma unroll
  for (int r = 0; r < 4; ++r) acc[r] = make_float4(0.f, 0.f, 0.f, 0.f);

  for (int kt = 0; kt < 4; ++kt) {
    __syncthreads();
    {
      const float4* W4 = (const float4*)(W + (size_t)(kt * 32) * 128);
      float4* Ws4 = (float4*)Ws;
#pragma unroll
      for (int i = 0; i < 4; ++i) Ws4[t + 256 * i] = W4[t + 256 * i];
    }
    {
      int r = t >> 3, c = t & 7;
      int gr = row0 + r;
      float4 v = make_float4(0.f, 0.f, 0.f, 0.f);
      if (gr < NN) v = ((const float4*)x)[(size_t)gr * 32 + kt * 8 + c];
      ((float4*)xs)[t] = v;
    }
    __syncthreads();
#pragma unroll
    for (int kk = 0; kk < 32; ++kk) {
      float4 wv = ((float4*)Ws)[kk * 32 + c4];
#pragma unroll
      for (int r = 0; r < 4; ++r) {
        float xv = xs[(ty + r * 8) * 32 + kk];
        acc[r].x += xv * wv.x; acc[r].y += xv * wv.y;
        acc[r].z += xv * wv.z; acc[r].w += xv * wv.w;
      }
    }
  }
#pragma unroll
  for (int r = 0; r < 4; ++r) {
    int gr = row0 + ty + r * 8;
    if (gr < NN) ((float4*)h)[(size_t)gr * 32 + c4] = acc[r];
  }
}

// ---------------- sym-normalized aggregate + bias (+ GELU) ----------------
__device__ inline float gelu_exact(float v) {
  return 0.5f * v * (1.0f + erff(v / 1.4142135623730951f));
}

__global__ __launch_bounds__(256) void agg_k(const float* __restrict__ h, const int* __restrict__ src,
                                             const float* __restrict__ dinv, const int* __restrict__ offs,
                                             const int* __restrict__ eids, const float* __restrict__ bias,
                                             float* __restrict__ xout, int act) {
  int lane = threadIdx.x & 63, w = threadIdx.x >> 6;
  int n = blockIdx.x * 4 + w;
  if (n >= NN) return;
  int s0 = offs[n], s1 = offs[n + 1];
  float dv = dinv[n];
  double a0 = 0.0, a1 = 0.0;
  for (int p = s0; p < s1; ++p) {
    int e = eids[p];
    int s = src[e];
    float norm = dinv[s] * dv;                       // f32 round like ref
    a0 += (double)(h[(size_t)s * CH + lane] * norm); // f32 product, f64 sum (order-insensitive)
    a1 += (double)(h[(size_t)s * CH + 64 + lane] * norm);
  }
  float selfn = dv * dv;  // self-loop appended last in ref
  a0 += (double)(h[(size_t)n * CH + lane] * selfn);
  a1 += (double)(h[(size_t)n * CH + 64 + lane] * selfn);
  float r0 = (float)a0 + bias[lane];
  float r1 = (float)a1 + bias[64 + lane];
  if (act) { r0 = gelu_exact(r0); r1 = gelu_exact(r1); }
  xout[(size_t)n * CH + lane] = r0;
  xout[(size_t)n * CH + 64 + lane] = r1;
}

// ---------------- confidence MLP + gumbel decision ----------------
template <bool LAST>
__global__ __launch_bounds__(256) void decide_k(const float* __restrict__ x, const float* __restrict__ W1,
                                                const float* __restrict__ b1, const float* __restrict__ W2,
                                                const float* __restrict__ b2, const float* __restrict__ gum,
                                                int* __restrict__ state, int* __restrict__ act,
                                                float* __restrict__ zout, float* __restrict__ eout,
                                                float layerf) {
  __shared__ float W1s[128 * 64];
  __shared__ float b1s[64];
  __shared__ float w2s[128];
  __shared__ float b2s[2];
  __shared__ float xrow[4][128];
  int t = threadIdx.x;
  {
    const float4* W14 = (const float4*)W1;
    float4* W1s4 = (float4*)W1s;
#pragma unroll
    for (int i = 0; i < 8; ++i) W1s4[t + 256 * i] = W14[t + 256 * i];
  }
  if (t < 64) b1s[t] = b1[t];
  if (t < 128) w2s[t] = W2[t];
  if (t < 2) b2s[t] = b2[t];

  int lane = t & 63, w = t >> 6;
  int n = blockIdx.x * 4 + w;
  bool valid = (n < NN);
  int st = valid ? state[n] : 1;
  float xa = 0.f, xb = 0.f;
  if (valid && st == 0) {
    xa = x[(size_t)n * CH + lane];
    xb = x[(size_t)n * CH + 64 + lane];
  }
  xrow[w][lane] = xa;
  xrow[w][64 + lane] = xb;
  __syncthreads();
  if (!valid || st != 0) return;

  // hidden_j = relu( sum_k x[k]*W1[k][j] + b1[j] ), lane j, f64 accumulate
  double acc = 0.0;
#pragma unroll 8
  for (int k = 0; k < 128; ++k)
    acc += (double)xrow[w][k] * (double)W1s[k * 64 + lane];
  float hid = fmaxf((float)acc + b1s[lane], 0.0f);

  double p0 = (double)hid * (double)w2s[lane * 2];
  double p1 = (double)hid * (double)w2s[lane * 2 + 1];
#pragma unroll
  for (int off = 32; off >= 1; off >>= 1) {
    p0 += __shfl_xor(p0, off);
    p1 += __shfl_xor(p1, off);
  }
  float l0 = (float)p0 + b2s[0];
  float l1 = (float)p1 + b2s[1];
  float g0 = gum[2 * (size_t)n];
  float g1 = gum[2 * (size_t)n + 1];
  // y1>y0 <=> (l1+g1)/temp > (l0+g0)/temp, temp>0 always
  bool ex = (l1 + g1) > (l0 + g0);

  if (LAST) {
    zout[(size_t)n * CH + lane] = xa;
    zout[(size_t)n * CH + 64 + lane] = xb;
    if (lane == 0) eout[n] = ex ? layerf : 3.0f;
  } else {
    if (ex) {
      zout[(size_t)n * CH + lane] = xa;
      zout[(size_t)n * CH + 64 + lane] = xb;
      if (lane == 0) { eout[n] = layerf; state[n] = 1; }
    } else {
      if (lane == 0) atomicAdd(act, 1);
    }
  }
}

__global__ void fin_k(const int* __restrict__ act, float* __restrict__ o) {
  if (threadIdx.x == 0 && blockIdx.x == 0) {
    o[0] = 50000.0f;
    o[1] = (float)act[0];
    o[2] = (float)act[1];
  }
}

// ---------------- host ----------------
extern "C" void kernel_launch(void* const* d_in, const int* in_sizes, int n_in,
                              void* d_out, int out_size, void* d_ws, size_t ws_size,
                              hipStream_t stream) {
  const float* x_in = (const float*)d_in[0];
  const int* eidx = (const int*)d_in[1];
  const int* esrc = eidx;
  const int* edst = eidx + NE;
  const float* convw[3] = {(const float*)d_in[2], (const float*)d_in[4], (const float*)d_in[6]};
  const float* convb[3] = {(const float*)d_in[3], (const float*)d_in[5], (const float*)d_in[7]};
  const float* cw1 = (const float*)d_in[8];
  const float* cb1 = (const float*)d_in[9];
  const float* cw2 = (const float*)d_in[10];
  const float* cb2 = (const float*)d_in[11];
  // d_in[12] = temp_w: unused (temperature is positive -> cancels in the argmax)

  float* out = (float*)d_out;
  float* zout = out;                       // [NN*CH]
  float* eout = out + (size_t)NN * CH;     // [NN]
  float* aout = eout + NN;                 // [3]

  char* w = (char*)d_ws;
  float* P = (float*)w;  w += (size_t)NN * CH * 4;   // h
  float* Q = (float*)w;  w += (size_t)NN * CH * 4;   // x (post-activation)
  int* eids = (int*)w;   w += (size_t)NE * 4;
  float* gum = (float*)w; w += (size_t)3 * NN * 2 * 4;
  int* offs = (int*)w;   w += (size_t)(NN + 1) * 4;
  float* dinv = (float*)w; w += (size_t)NN * 4;
  char* zr0 = w;                                     // zero region: degi,cnt,state,act
  int* degi = (int*)w;   w += (size_t)NN * 4;
  int* cnt = (int*)w;    w += (size_t)NN * 4;
  int* state = (int*)w;  w += (size_t)NN * 4;
  int* act = (int*)w;    w += 64;
  int* parts = (int*)w;  w += 1024;

  hipMemsetAsync(zr0, 0, (size_t)(3 * NN) * 4 + 64, stream);

  // layer keys: fold_in(key(42), l) = threefry2x32((0,42),(0,l))
  uint32_t key[3][2];
  for (int l = 0; l < 3; ++l) {
    uint32_t a = 0u, b = (uint32_t)l;
    tf2x32(0u, 42u, a, b);
    key[l][0] = a; key[l][1] = b;
  }

  const int nblkN = (NN + 255) / 256;  // 196
  deg_k<<<(NE + 255) / 256, 256, 0, stream>>>(edst, degi);
  dinv_k<<<nblkN, 256, 0, stream>>>(degi, dinv);
  scan1_k<<<nblkN, 256, 0, stream>>>(degi, offs, parts);
  scan2_k<<<1, 64, 0, stream>>>(parts, nblkN);
  scan3_k<<<nblkN, 256, 0, stream>>>(offs, parts);
  place_k<<<(NE + 255) / 256, 256, 0, stream>>>(edst, offs, cnt, eids);
  sort_k<<<nblkN, 256, 0, stream>>>(offs, eids);
  gum_k<<<(3 * NN + 255) / 256, 256, 0, stream>>>(gum, key[0][0], key[0][1], key[1][0], key[1][1],
                                                  key[2][0], key[2][1]);

  for (int l = 0; l < 3; ++l) {
    const float* xin = (l == 0) ? x_in : Q;
    lin_k<<<(NN + 31) / 32, 256, 0, stream>>>(xin, convw[l], P);
    agg_k<<<NN / 4, 256, 0, stream>>>(P, esrc, dinv, offs, eids, convb[l], Q, (l < 2) ? 1 : 0);
    if (l < 2)
      decide_k<false><<<NN / 4, 256, 0, stream>>>(Q, cw1, cb1, cw2, cb2, gum + (size_t)l * NN * 2,
                                                  state, act + l, zout, eout, (float)l);
    else
      decide_k<true><<<NN / 4, 256, 0, stream>>>(Q, cw1, cb1, cw2, cb2, gum + (size_t)l * NN * 2,
                                                 state, act, zout, eout, (float)l);
  }
  fin_k<<<1, 64, 0, stream>>>(act, aout);
}

// Round 3
// 764.692 us; speedup vs baseline: 1.4541x; 1.4541x over previous
//
#include <hip/hip_runtime.h>
#include <stdint.h>

#define NN 50000
#define NE 800000
#define CH 128

// ---------------- threefry2x32 (exact JAX semantics) ----------------
__host__ __device__ inline void tf2x32(uint32_t k0, uint32_t k1, uint32_t& x0, uint32_t& x1) {
  uint32_t ks2 = k0 ^ k1 ^ 0x1BD11BDAu;
  x0 += k0; x1 += k1;
#define ROTL(v, r) (((v) << (r)) | ((v) >> (32 - (r))))
#define RND(r) { x0 += x1; x1 = ROTL(x1, r); x1 ^= x0; }
  RND(13) RND(15) RND(26) RND(6)
  x0 += k1; x1 += ks2 + 1u;
  RND(17) RND(29) RND(16) RND(24)
  x0 += ks2; x1 += k0 + 2u;
  RND(13) RND(15) RND(26) RND(6)
  x0 += k0; x1 += k1 + 3u;
  RND(17) RND(29) RND(16) RND(24)
  x0 += k1; x1 += ks2 + 4u;
  RND(13) RND(15) RND(26) RND(6)
  x0 += ks2; x1 += k0 + 5u;
#undef RND
#undef ROTL
}

__device__ inline float bits_to_u(uint32_t b) {
  float f = __uint_as_float(0x3F800000u | (b >> 9)) - 1.0f;  // [0,1)
  f = f + 1e-10f;
  return fmaxf(1e-10f, f);
}

// ---------------- graph preprocessing ----------------
__global__ __launch_bounds__(256) void deg_k(const int* __restrict__ dst, int* __restrict__ degi) {
  int i = blockIdx.x * 256 + threadIdx.x;
  if (i < NE) atomicAdd(&degi[dst[i]], 1);
}

__global__ __launch_bounds__(256) void dinv_k(const int* __restrict__ degi, float* __restrict__ dinv) {
  int n = blockIdx.x * 256 + threadIdx.x;
  if (n < NN) {
    float d = (float)(degi[n] + 1);
    dinv[n] = 1.0f / sqrtf(d);
  }
}

__global__ __launch_bounds__(256) void scan1_k(const int* __restrict__ degi, int* __restrict__ offs,
                                               int* __restrict__ part) {
  __shared__ int tmp[256];
  int t = threadIdx.x, b = blockIdx.x, i = b * 256 + t;
  int v = (i < NN) ? degi[i] : 0;
  tmp[t] = v;
  __syncthreads();
  for (int s = 1; s < 256; s <<= 1) {
    int a = (t >= s) ? tmp[t - s] : 0;
    __syncthreads();
    tmp[t] += a;
    __syncthreads();
  }
  int incl = tmp[t];
  if (i < NN) offs[i] = incl - v;
  if (t == 255) part[b] = incl;
}

__global__ void scan2_k(int* part, int nparts) {
  if (threadIdx.x == 0 && blockIdx.x == 0) {
    int run = 0;
    for (int i = 0; i < nparts; ++i) { int v = part[i]; part[i] = run; run += v; }
  }
}

__global__ __launch_bounds__(256) void scan3_k(int* __restrict__ offs, const int* __restrict__ part) {
  int i = blockIdx.x * 256 + threadIdx.x;
  if (i < NN) offs[i] += part[blockIdx.x];
  if (i == 0) offs[NN] = NE;
}

__global__ __launch_bounds__(256) void place_k(const int* __restrict__ dst, const int* __restrict__ offs,
                                               int* __restrict__ cnt, int* __restrict__ eids) {
  int i = blockIdx.x * 256 + threadIdx.x;
  if (i < NE) {
    int d = dst[i];
    int p = offs[d] + atomicAdd(&cnt[d], 1);
    eids[p] = i;
  }
}

// deterministic intra-bucket order = ascending edge id (matches ref segment-sum order)
__global__ __launch_bounds__(256) void sort_k(const int* __restrict__ offs, int* __restrict__ eids) {
  int n = blockIdx.x * 256 + threadIdx.x;
  if (n >= NN) return;
  int s0 = offs[n], s1 = offs[n + 1];
  for (int i = s0 + 1; i < s1; ++i) {
    int v = eids[i];
    int j = i - 1;
    while (j >= s0 && eids[j] > v) { eids[j + 1] = eids[j]; --j; }
    eids[j + 1] = v;
  }
}

// gather src + norm per sorted edge slot; srcs may alias eids (in-place, own-slot RMW)
__global__ __launch_bounds__(256) void gath_k(const int* __restrict__ eids, const int* __restrict__ src,
                                              const int* __restrict__ dst, const float* __restrict__ dinv,
                                              int* __restrict__ srcs, float* __restrict__ norms) {
  int p = blockIdx.x * 256 + threadIdx.x;
  if (p < NE) {
    int e = eids[p];
    int s = src[e];
    float nm = dinv[s] * dinv[dst[e]];  // f32 round, same as passing version
    srcs[p] = s;
    norms[p] = nm;
  }
}

// ---------------- gumbel precompute ----------------
__global__ __launch_bounds__(256) void gum_k(float* __restrict__ gum,
                                             uint32_t k00, uint32_t k01, uint32_t k10, uint32_t k11,
                                             uint32_t k20, uint32_t k21) {
  int i = blockIdx.x * 256 + threadIdx.x;
  if (i >= 3 * NN) return;
  int l = i / NN;
  int n = i - l * NN;
  uint32_t kx, ky;
  if (l == 0) { kx = k00; ky = k01; }
  else if (l == 1) { kx = k10; ky = k11; }
  else { kx = k20; ky = k21; }
  int j0 = 2 * n, j1 = 2 * n + 1;
  uint32_t w0, w1;
  if (j0 < NN) {
    uint32_t a0 = (uint32_t)j0, a1 = (uint32_t)(j0 + NN);
    tf2x32(kx, ky, a0, a1); w0 = a0;
    uint32_t b0 = (uint32_t)j1, b1 = (uint32_t)(j1 + NN);
    tf2x32(kx, ky, b0, b1); w1 = b0;
  } else {
    uint32_t a0 = (uint32_t)(j0 - NN), a1 = (uint32_t)j0;
    tf2x32(kx, ky, a0, a1); w0 = a1;
    uint32_t b0 = (uint32_t)(j1 - NN), b1 = (uint32_t)j1;
    tf2x32(kx, ky, b0, b1); w1 = b1;
  }
  float u0 = bits_to_u(w0), u1 = bits_to_u(w1);
  gum[2 * (size_t)i]     = -logf(-logf(u0));
  gum[2 * (size_t)i + 1] = -logf(-logf(u1));
}

// ---------------- h = x @ W  (f32, 32x128 tile, BK=32) ----------------
__global__ __launch_bounds__(256) void lin_k(const float* __restrict__ x, const float* __restrict__ W,
                                             float* __restrict__ h) {
  __shared__ float Ws[32 * 128];
  __shared__ float xs[32 * 32];
  int t = threadIdx.x;
  int row0 = blockIdx.x << 5;
  int c4 = t & 31;
  int ty = t >> 5;
  float4 acc[4];
#pragma unroll
  for (int r = 0; r < 4; ++r) acc[r] = make_float4(0.f, 0.f, 0.f, 0.f);

  for (int kt = 0; kt < 4; ++kt) {
    __syncthreads();
    {
      const float4* W4 = (const float4*)(W + (size_t)(kt * 32) * 128);
      float4* Ws4 = (float4*)Ws;
#pragma unroll
      for (int i = 0; i < 4; ++i) Ws4[t + 256 * i] = W4[t + 256 * i];
    }
    {
      int r = t >> 3, c = t & 7;
      int gr = row0 + r;
      float4 v = make_float4(0.f, 0.f, 0.f, 0.f);
      if (gr < NN) v = ((const float4*)x)[(size_t)gr * 32 + kt * 8 + c];
      ((float4*)xs)[t] = v;
    }
    __syncthreads();
#pragma unroll
    for (int kk = 0; kk < 32; ++kk) {
      float4 wv = ((float4*)Ws)[kk * 32 + c4];
#pragma unroll
      for (int r = 0; r < 4; ++r) {
        float xv = xs[(ty + r * 8) * 32 + kk];
        acc[r].x += xv * wv.x; acc[r].y += xv * wv.y;
        acc[r].z += xv * wv.z; acc[r].w += xv * wv.w;
      }
    }
  }
#pragma unroll
  for (int r = 0; r < 4; ++r) {
    int gr = row0 + ty + r * 8;
    if (gr < NN) ((float4*)h)[(size_t)gr * 32 + c4] = acc[r];
  }
}

// ---------------- sym-normalized aggregate + bias (+ GELU) ----------------
__device__ inline float gelu_exact(float v) {
  return 0.5f * v * (1.0f + erff(v / 1.4142135623730951f));
}

// wave per node, channels (2*lane, 2*lane+1); edge descriptors lane-parallel-loaded,
// shfl-broadcast, 4-way unrolled so h-row loads pipeline.
__global__ __launch_bounds__(256) void agg_k(const float* __restrict__ h, const float* __restrict__ dinv,
                                             const int* __restrict__ offs, const int* __restrict__ srcs,
                                             const float* __restrict__ norms, const float* __restrict__ bias,
                                             float* __restrict__ xout, int act) {
  int lane = threadIdx.x & 63, w = threadIdx.x >> 6;
  int n = blockIdx.x * 4 + w;
  if (n >= NN) return;
  int s0 = offs[n], s1 = offs[n + 1];
  double a0 = 0.0, a1 = 0.0;
  for (int p0 = s0; p0 < s1; p0 += 64) {
    int m = s1 - p0; if (m > 64) m = 64;
    int sv = 0; float nv = 0.f;
    if (lane < m) { sv = srcs[p0 + lane]; nv = norms[p0 + lane]; }
    int i = 0;
    for (; i + 4 <= m; i += 4) {
      int   sA = __shfl(sv, i),     sB = __shfl(sv, i + 1), sC = __shfl(sv, i + 2), sD = __shfl(sv, i + 3);
      float nA = __shfl(nv, i),     nB = __shfl(nv, i + 1), nC = __shfl(nv, i + 2), nD = __shfl(nv, i + 3);
      float2 hA = *(const float2*)&h[(size_t)sA * CH + 2 * lane];
      float2 hB = *(const float2*)&h[(size_t)sB * CH + 2 * lane];
      float2 hC = *(const float2*)&h[(size_t)sC * CH + 2 * lane];
      float2 hD = *(const float2*)&h[(size_t)sD * CH + 2 * lane];
      a0 += (double)(hA.x * nA); a1 += (double)(hA.y * nA);
      a0 += (double)(hB.x * nB); a1 += (double)(hB.y * nB);
      a0 += (double)(hC.x * nC); a1 += (double)(hC.y * nC);
      a0 += (double)(hD.x * nD); a1 += (double)(hD.y * nD);
    }
    for (; i < m; ++i) {
      int   s = __shfl(sv, i);
      float nm = __shfl(nv, i);
      float2 hv = *(const float2*)&h[(size_t)s * CH + 2 * lane];
      a0 += (double)(hv.x * nm); a1 += (double)(hv.y * nm);
    }
  }
  float dv = dinv[n];
  float selfn = dv * dv;  // self-loop appended last, like ref
  float2 hn = *(const float2*)&h[(size_t)n * CH + 2 * lane];
  a0 += (double)(hn.x * selfn); a1 += (double)(hn.y * selfn);
  float r0 = (float)a0 + bias[2 * lane];
  float r1 = (float)a1 + bias[2 * lane + 1];
  if (act) { r0 = gelu_exact(r0); r1 = gelu_exact(r1); }
  float2 o; o.x = r0; o.y = r1;
  *(float2*)&xout[(size_t)n * CH + 2 * lane] = o;
}

// ---------------- confidence MLP + gumbel decision ----------------
// MODE 0: first layer (no state read, count non-exits)
// MODE 1: middle layer (state read, count non-exits)
// MODE 2: last layer (state read, all active nodes write z)
#define DNPB 16

template <int MODE>
__global__ __launch_bounds__(256) void decide_k(const float* __restrict__ x, const float* __restrict__ W1,
                                                const float* __restrict__ b1, const float* __restrict__ W2,
                                                const float* __restrict__ b2, const float* __restrict__ gum,
                                                int* __restrict__ state, int* __restrict__ act,
                                                float* __restrict__ zout, float* __restrict__ eout,
                                                float layerf) {
  __shared__ float W1s[128 * 64];
  __shared__ float b1s[64];
  __shared__ float w2s[128];
  __shared__ float b2s[2];
  __shared__ float xs[DNPB][128];
  __shared__ int sts[DNPB];
  int t = threadIdx.x;
#pragma unroll
  for (int i = 0; i < 8; ++i) ((float4*)W1s)[t + 256 * i] = ((const float4*)W1)[t + 256 * i];
  if (t < 64) b1s[t] = b1[t];
  if (t < 128) w2s[t] = W2[t];
  if (t < 2) b2s[t] = b2[t];
  int lane = t & 63, w = t >> 6;

  for (int base = blockIdx.x * DNPB; base < NN; base += gridDim.x * DNPB) {
    __syncthreads();  // previous chunk's reads of xs/sts done (also covers W1s before 1st use)
    if (MODE > 0) {
      if (t < DNPB) sts[t] = state[base + t];
    }
    __syncthreads();
    if (MODE > 0) {
      int any = 0;
#pragma unroll
      for (int i = 0; i < DNPB; ++i) any |= (sts[i] == 0);
      if (!any) continue;  // block-uniform
    }
    // stage 16 x-rows (16*32 float4), 2 per thread
#pragma unroll
    for (int i = 0; i < 2; ++i) {
      int fi = t + 256 * i;
      int nr = fi >> 5, cc = fi & 31;
      ((float4*)xs)[fi] = ((const float4*)x)[((size_t)(base + nr)) * 32 + cc];
    }
    __syncthreads();

    int q = w * 4;
    int n0 = base + q;
    int m0 = 1, m1 = 1, m2 = 1, m3 = 1;
    if (MODE > 0) { m0 = (sts[q] == 0); m1 = (sts[q + 1] == 0); m2 = (sts[q + 2] == 0); m3 = (sts[q + 3] == 0); }
    if (!(m0 | m1 | m2 | m3)) continue;

    const float* r0 = xs[q + 0];
    const float* r1 = xs[q + 1];
    const float* r2 = xs[q + 2];
    const float* r3 = xs[q + 3];
    // 4 independent f64 chains; per-node k-ascending order identical to the verified version
    double a0 = 0.0, a1 = 0.0, a2 = 0.0, a3 = 0.0;
#pragma unroll
    for (int k = 0; k < 128; k += 4) {
      float wv0 = W1s[(k + 0) * 64 + lane];
      float wv1 = W1s[(k + 1) * 64 + lane];
      float wv2 = W1s[(k + 2) * 64 + lane];
      float wv3 = W1s[(k + 3) * 64 + lane];
      float4 va = *(const float4*)&r0[k];
      float4 vb = *(const float4*)&r1[k];
      float4 vc = *(const float4*)&r2[k];
      float4 vd = *(const float4*)&r3[k];
      a0 += (double)va.x * (double)wv0; a0 += (double)va.y * (double)wv1;
      a0 += (double)va.z * (double)wv2; a0 += (double)va.w * (double)wv3;
      a1 += (double)vb.x * (double)wv0; a1 += (double)vb.y * (double)wv1;
      a1 += (double)vb.z * (double)wv2; a1 += (double)vb.w * (double)wv3;
      a2 += (double)vc.x * (double)wv0; a2 += (double)vc.y * (double)wv1;
      a2 += (double)vc.z * (double)wv2; a2 += (double)vc.w * (double)wv3;
      a3 += (double)vd.x * (double)wv0; a3 += (double)vd.y * (double)wv1;
      a3 += (double)vd.z * (double)wv2; a3 += (double)vd.w * (double)wv3;
    }
    float hid0 = fmaxf((float)a0 + b1s[lane], 0.0f);
    float hid1 = fmaxf((float)a1 + b1s[lane], 0.0f);
    float hid2 = fmaxf((float)a2 + b1s[lane], 0.0f);
    float hid3 = fmaxf((float)a3 + b1s[lane], 0.0f);
    float wA = w2s[lane * 2], wB = w2s[lane * 2 + 1];
    double p00 = (double)hid0 * (double)wA, p01 = (double)hid0 * (double)wB;
    double p10 = (double)hid1 * (double)wA, p11 = (double)hid1 * (double)wB;
    double p20 = (double)hid2 * (double)wA, p21 = (double)hid2 * (double)wB;
    double p30 = (double)hid3 * (double)wA, p31 = (double)hid3 * (double)wB;
#pragma unroll
    for (int off = 32; off >= 1; off >>= 1) {
      p00 += __shfl_xor(p00, off); p01 += __shfl_xor(p01, off);
      p10 += __shfl_xor(p10, off); p11 += __shfl_xor(p11, off);
      p20 += __shfl_xor(p20, off); p21 += __shfl_xor(p21, off);
      p30 += __shfl_xor(p30, off); p31 += __shfl_xor(p31, off);
    }
    float4 ga = *(const float4*)&gum[2 * (size_t)n0];        // g0,g1 of nodes 0,1
    float4 gb = *(const float4*)&gum[2 * (size_t)n0 + 4];    // g0,g1 of nodes 2,3
    bool ex0 = (((float)p01 + b2s[1]) + ga.y) > (((float)p00 + b2s[0]) + ga.x);
    bool ex1 = (((float)p11 + b2s[1]) + ga.w) > (((float)p10 + b2s[0]) + ga.z);
    bool ex2 = (((float)p21 + b2s[1]) + gb.y) > (((float)p20 + b2s[0]) + gb.x);
    bool ex3 = (((float)p31 + b2s[1]) + gb.w) > (((float)p30 + b2s[0]) + gb.z);

    int cnt = 0;
    int mm[4] = {m0, m1, m2, m3};
    bool ee[4] = {ex0, ex1, ex2, ex3};
#pragma unroll
    for (int i = 0; i < 4; ++i) {
      if (!mm[i]) continue;
      int n = n0 + i;
      if (MODE == 2) {
        float2 v = *(const float2*)&xs[q + i][2 * lane];
        *(float2*)&zout[(size_t)n * CH + 2 * lane] = v;
        if (lane == 0) eout[n] = ee[i] ? layerf : 3.0f;
      } else {
        if (ee[i]) {
          float2 v = *(const float2*)&xs[q + i][2 * lane];
          *(float2*)&zout[(size_t)n * CH + 2 * lane] = v;
          if (lane == 0) { eout[n] = layerf; state[n] = 1; }
        } else {
          ++cnt;
        }
      }
    }
    if (MODE != 2 && lane == 0 && cnt) atomicAdd(act, cnt);
  }
}

__global__ void fin_k(const int* __restrict__ act, float* __restrict__ o) {
  if (threadIdx.x == 0 && blockIdx.x == 0) {
    o[0] = 50000.0f;
    o[1] = (float)act[0];
    o[2] = (float)act[1];
  }
}

// ---------------- host ----------------
extern "C" void kernel_launch(void* const* d_in, const int* in_sizes, int n_in,
                              void* d_out, int out_size, void* d_ws, size_t ws_size,
                              hipStream_t stream) {
  const float* x_in = (const float*)d_in[0];
  const int* eidx = (const int*)d_in[1];
  const int* esrc = eidx;
  const int* edst = eidx + NE;
  const float* convw[3] = {(const float*)d_in[2], (const float*)d_in[4], (const float*)d_in[6]};
  const float* convb[3] = {(const float*)d_in[3], (const float*)d_in[5], (const float*)d_in[7]};
  const float* cw1 = (const float*)d_in[8];
  const float* cb1 = (const float*)d_in[9];
  const float* cw2 = (const float*)d_in[10];
  const float* cb2 = (const float*)d_in[11];
  // d_in[12] = temp_w: unused (temperature > 0 cancels in the argmax)

  float* out = (float*)d_out;
  float* zout = out;
  float* eout = out + (size_t)NN * CH;
  float* aout = eout + NN;

  char* w = (char*)d_ws;
  float* P = (float*)w;   w += (size_t)NN * CH * 4;
  float* Q = (float*)w;   w += (size_t)NN * CH * 4;
  int* eids = (int*)w;    w += (size_t)NE * 4;      // becomes srcs in-place after gath_k
  float* norms = (float*)w; w += (size_t)NE * 4;
  float* gum = (float*)w; w += (size_t)3 * NN * 2 * 4;
  int* offs = (int*)w;    w += (size_t)(NN + 1) * 4;
  float* dinv = (float*)w; w += (size_t)NN * 4;
  char* zr0 = w;
  int* degi = (int*)w;    w += (size_t)NN * 4;
  int* cnt = (int*)w;     w += (size_t)NN * 4;
  int* state = (int*)w;   w += (size_t)NN * 4;
  int* act = (int*)w;     w += 64;
  int* parts = (int*)w;   w += 1024;

  hipMemsetAsync(zr0, 0, (size_t)(3 * NN) * 4 + 64, stream);

  uint32_t key[3][2];
  for (int l = 0; l < 3; ++l) {
    uint32_t a = 0u, b = (uint32_t)l;
    tf2x32(0u, 42u, a, b);
    key[l][0] = a; key[l][1] = b;
  }

  const int nblkN = (NN + 255) / 256;
  deg_k<<<(NE + 255) / 256, 256, 0, stream>>>(edst, degi);
  dinv_k<<<nblkN, 256, 0, stream>>>(degi, dinv);
  scan1_k<<<nblkN, 256, 0, stream>>>(degi, offs, parts);
  scan2_k<<<1, 64, 0, stream>>>(parts, nblkN);
  scan3_k<<<nblkN, 256, 0, stream>>>(offs, parts);
  place_k<<<(NE + 255) / 256, 256, 0, stream>>>(edst, offs, cnt, eids);
  sort_k<<<nblkN, 256, 0, stream>>>(offs, eids);
  gath_k<<<(NE + 255) / 256, 256, 0, stream>>>(eids, esrc, edst, dinv, eids, norms);
  gum_k<<<(3 * NN + 255) / 256, 256, 0, stream>>>(gum, key[0][0], key[0][1], key[1][0], key[1][1],
                                                  key[2][0], key[2][1]);

  const int DG = 782;  // decide grid: ~3 blocks/CU at ~41KB LDS, grid-stride over 3125 chunks
  for (int l = 0; l < 3; ++l) {
    const float* xin = (l == 0) ? x_in : Q;
    lin_k<<<(NN + 31) / 32, 256, 0, stream>>>(xin, convw[l], P);
    agg_k<<<NN / 4, 256, 0, stream>>>(P, dinv, offs, eids, norms, convb[l], Q, (l < 2) ? 1 : 0);
    if (l == 0)
      decide_k<0><<<DG, 256, 0, stream>>>(Q, cw1, cb1, cw2, cb2, gum, state, act + 0, zout, eout, 0.0f);
    else if (l == 1)
      decide_k<1><<<DG, 256, 0, stream>>>(Q, cw1, cb1, cw2, cb2, gum + (size_t)NN * 2, state, act + 1,
                                          zout, eout, 1.0f);
    else
      decide_k<2><<<DG, 256, 0, stream>>>(Q, cw1, cb1, cw2, cb2, gum + (size_t)2 * NN * 2, state, act,
                                          zout, eout, 2.0f);
  }
  fin_k<<<1, 64, 0, stream>>>(act, aout);
}

// Round 4
// 597.133 us; speedup vs baseline: 1.8622x; 1.2806x over previous
//
#include <hip/hip_runtime.h>
#include <stdint.h>

#define NN 50000
#define NE 800000
#define CH 128

typedef double d4 __attribute__((ext_vector_type(4)));

// ---------------- threefry2x32 (exact JAX semantics) ----------------
__host__ __device__ inline void tf2x32(uint32_t k0, uint32_t k1, uint32_t& x0, uint32_t& x1) {
  uint32_t ks2 = k0 ^ k1 ^ 0x1BD11BDAu;
  x0 += k0; x1 += k1;
#define ROTL(v, r) (((v) << (r)) | ((v) >> (32 - (r))))
#define RND(r) { x0 += x1; x1 = ROTL(x1, r); x1 ^= x0; }
  RND(13) RND(15) RND(26) RND(6)
  x0 += k1; x1 += ks2 + 1u;
  RND(17) RND(29) RND(16) RND(24)
  x0 += ks2; x1 += k0 + 2u;
  RND(13) RND(15) RND(26) RND(6)
  x0 += k0; x1 += k1 + 3u;
  RND(17) RND(29) RND(16) RND(24)
  x0 += k1; x1 += ks2 + 4u;
  RND(13) RND(15) RND(26) RND(6)
  x0 += ks2; x1 += k0 + 5u;
#undef RND
#undef ROTL
}

__device__ inline float bits_to_u(uint32_t b) {
  float f = __uint_as_float(0x3F800000u | (b >> 9)) - 1.0f;  // [0,1)
  f = f + 1e-10f;
  return fmaxf(1e-10f, f);
}

// ---------------- graph preprocessing ----------------
__global__ __launch_bounds__(256) void deg_k(const int* __restrict__ dst, int* __restrict__ degi) {
  int i = blockIdx.x * 256 + threadIdx.x;
  if (i < NE) atomicAdd(&degi[dst[i]], 1);
}

__global__ __launch_bounds__(256) void dinv_k(const int* __restrict__ degi, float* __restrict__ dinv) {
  int n = blockIdx.x * 256 + threadIdx.x;
  if (n < NN) {
    float d = (float)(degi[n] + 1);
    dinv[n] = 1.0f / sqrtf(d);
  }
}

__global__ __launch_bounds__(256) void scan1_k(const int* __restrict__ degi, int* __restrict__ offs,
                                               int* __restrict__ part) {
  __shared__ int tmp[256];
  int t = threadIdx.x, b = blockIdx.x, i = b * 256 + t;
  int v = (i < NN) ? degi[i] : 0;
  tmp[t] = v;
  __syncthreads();
  for (int s = 1; s < 256; s <<= 1) {
    int a = (t >= s) ? tmp[t - s] : 0;
    __syncthreads();
    tmp[t] += a;
    __syncthreads();
  }
  int incl = tmp[t];
  if (i < NN) offs[i] = incl - v;
  if (t == 255) part[b] = incl;
}

__global__ void scan2_k(int* part, int nparts) {
  if (threadIdx.x == 0 && blockIdx.x == 0) {
    int run = 0;
    for (int i = 0; i < nparts; ++i) { int v = part[i]; part[i] = run; run += v; }
  }
}

__global__ __launch_bounds__(256) void scan3_k(int* __restrict__ offs, const int* __restrict__ part) {
  int i = blockIdx.x * 256 + threadIdx.x;
  if (i < NN) offs[i] += part[blockIdx.x];
  if (i == 0) offs[NN] = NE;
}

__global__ __launch_bounds__(256) void place_k(const int* __restrict__ dst, const int* __restrict__ offs,
                                               int* __restrict__ cnt, int* __restrict__ eids) {
  int i = blockIdx.x * 256 + threadIdx.x;
  if (i < NE) {
    int d = dst[i];
    int p = offs[d] + atomicAdd(&cnt[d], 1);
    eids[p] = i;
  }
}

// deterministic intra-bucket order = ascending edge id (matches ref segment-sum order)
__global__ __launch_bounds__(256) void sort_k(const int* __restrict__ offs, int* __restrict__ eids) {
  int n = blockIdx.x * 256 + threadIdx.x;
  if (n >= NN) return;
  int s0 = offs[n], s1 = offs[n + 1];
  for (int i = s0 + 1; i < s1; ++i) {
    int v = eids[i];
    int j = i - 1;
    while (j >= s0 && eids[j] > v) { eids[j + 1] = eids[j]; --j; }
    eids[j + 1] = v;
  }
}

// gather src + norm per sorted edge slot; srcs may alias eids (in-place, own-slot RMW)
__global__ __launch_bounds__(256) void gath_k(const int* __restrict__ eids, const int* __restrict__ src,
                                              const int* __restrict__ dst, const float* __restrict__ dinv,
                                              int* __restrict__ srcs, float* __restrict__ norms) {
  int p = blockIdx.x * 256 + threadIdx.x;
  if (p < NE) {
    int e = eids[p];
    int s = src[e];
    float nm = dinv[s] * dinv[dst[e]];
    srcs[p] = s;
    norms[p] = nm;
  }
}

// ---------------- gumbel precompute ----------------
__global__ __launch_bounds__(256) void gum_k(float* __restrict__ gum,
                                             uint32_t k00, uint32_t k01, uint32_t k10, uint32_t k11,
                                             uint32_t k20, uint32_t k21) {
  int i = blockIdx.x * 256 + threadIdx.x;
  if (i >= 3 * NN) return;
  int l = i / NN;
  int n = i - l * NN;
  uint32_t kx, ky;
  if (l == 0) { kx = k00; ky = k01; }
  else if (l == 1) { kx = k10; ky = k11; }
  else { kx = k20; ky = k21; }
  int j0 = 2 * n, j1 = 2 * n + 1;
  uint32_t w0, w1;
  if (j0 < NN) {
    uint32_t a0 = (uint32_t)j0, a1 = (uint32_t)(j0 + NN);
    tf2x32(kx, ky, a0, a1); w0 = a0;
    uint32_t b0 = (uint32_t)j1, b1 = (uint32_t)(j1 + NN);
    tf2x32(kx, ky, b0, b1); w1 = b0;
  } else {
    uint32_t a0 = (uint32_t)(j0 - NN), a1 = (uint32_t)j0;
    tf2x32(kx, ky, a0, a1); w0 = a1;
    uint32_t b0 = (uint32_t)(j1 - NN), b1 = (uint32_t)j1;
    tf2x32(kx, ky, b0, b1); w1 = b1;
  }
  float u0 = bits_to_u(w0), u1 = bits_to_u(w1);
  gum[2 * (size_t)i]     = -logf(-logf(u0));
  gum[2 * (size_t)i + 1] = -logf(-logf(u1));
}

// ---------------- h = x @ W  (f32, 32x128 tile, BK=32) ----------------
__global__ __launch_bounds__(256) void lin_k(const float* __restrict__ x, const float* __restrict__ W,
                                             float* __restrict__ h) {
  __shared__ float Ws[32 * 128];
  __shared__ float xs[32 * 32];
  int t = threadIdx.x;
  int row0 = blockIdx.x << 5;
  int c4 = t & 31;
  int ty = t >> 5;
  float4 acc[4];
#pragma unroll
  for (int r = 0; r < 4; ++r) acc[r] = make_float4(0.f, 0.f, 0.f, 0.f);

  for (int kt = 0; kt < 4; ++kt) {
    __syncthreads();
    {
      const float4* W4 = (const float4*)(W + (size_t)(kt * 32) * 128);
      float4* Ws4 = (float4*)Ws;
#pragma unroll
      for (int i = 0; i < 4; ++i) Ws4[t + 256 * i] = W4[t + 256 * i];
    }
    {
      int r = t >> 3, c = t & 7;
      int gr = row0 + r;
      float4 v = make_float4(0.f, 0.f, 0.f, 0.f);
      if (gr < NN) v = ((const float4*)x)[(size_t)gr * 32 + kt * 8 + c];
      ((float4*)xs)[t] = v;
    }
    __syncthreads();
#pragma unroll
    for (int kk = 0; kk < 32; ++kk) {
      float4 wv = ((float4*)Ws)[kk * 32 + c4];
#pragma unroll
      for (int r = 0; r < 4; ++r) {
        float xv = xs[(ty + r * 8) * 32 + kk];
        acc[r].x += xv * wv.x; acc[r].y += xv * wv.y;
        acc[r].z += xv * wv.z; acc[r].w += xv * wv.w;
      }
    }
  }
#pragma unroll
  for (int r = 0; r < 4; ++r) {
    int gr = row0 + ty + r * 8;
    if (gr < NN) ((float4*)h)[(size_t)gr * 32 + c4] = acc[r];
  }
}

// ---------------- sym-normalized aggregate + bias (+ GELU) ----------------
__device__ inline float gelu_exact(float v) {
  return 0.5f * v * (1.0f + erff(v / 1.4142135623730951f));
}

__global__ __launch_bounds__(256) void agg_k(const float* __restrict__ h, const float* __restrict__ dinv,
                                             const int* __restrict__ offs, const int* __restrict__ srcs,
                                             const float* __restrict__ norms, const float* __restrict__ bias,
                                             float* __restrict__ xout, int act) {
  int lane = threadIdx.x & 63, w = threadIdx.x >> 6;
  int n = blockIdx.x * 4 + w;
  if (n >= NN) return;
  int s0 = offs[n], s1 = offs[n + 1];
  double a0 = 0.0, a1 = 0.0;
  for (int p0 = s0; p0 < s1; p0 += 64) {
    int m = s1 - p0; if (m > 64) m = 64;
    int sv = 0; float nv = 0.f;
    if (lane < m) { sv = srcs[p0 + lane]; nv = norms[p0 + lane]; }
    int i = 0;
    for (; i + 4 <= m; i += 4) {
      int   sA = __shfl(sv, i),     sB = __shfl(sv, i + 1), sC = __shfl(sv, i + 2), sD = __shfl(sv, i + 3);
      float nA = __shfl(nv, i),     nB = __shfl(nv, i + 1), nC = __shfl(nv, i + 2), nD = __shfl(nv, i + 3);
      float2 hA = *(const float2*)&h[(size_t)sA * CH + 2 * lane];
      float2 hB = *(const float2*)&h[(size_t)sB * CH + 2 * lane];
      float2 hC = *(const float2*)&h[(size_t)sC * CH + 2 * lane];
      float2 hD = *(const float2*)&h[(size_t)sD * CH + 2 * lane];
      a0 += (double)(hA.x * nA); a1 += (double)(hA.y * nA);
      a0 += (double)(hB.x * nB); a1 += (double)(hB.y * nB);
      a0 += (double)(hC.x * nC); a1 += (double)(hC.y * nC);
      a0 += (double)(hD.x * nD); a1 += (double)(hD.y * nD);
    }
    for (; i < m; ++i) {
      int   s = __shfl(sv, i);
      float nm = __shfl(nv, i);
      float2 hv = *(const float2*)&h[(size_t)s * CH + 2 * lane];
      a0 += (double)(hv.x * nm); a1 += (double)(hv.y * nm);
    }
  }
  float dv = dinv[n];
  float selfn = dv * dv;  // self-loop appended last, like ref
  float2 hn = *(const float2*)&h[(size_t)n * CH + 2 * lane];
  a0 += (double)(hn.x * selfn); a1 += (double)(hn.y * selfn);
  float r0 = (float)a0 + bias[2 * lane];
  float r1 = (float)a1 + bias[2 * lane + 1];
  if (act) { r0 = gelu_exact(r0); r1 = gelu_exact(r1); }
  float2 o; o.x = r0; o.y = r1;
  *(float2*)&xout[(size_t)n * CH + 2 * lane] = o;
}

// ---------------- confidence MLP + gumbel decision via f64 MFMA ----------------
// Block = 4 waves; wave = one 16-node M-tile. hidden = relu(f32(X@W1_f64mfma)+b1),
// logits via in-register f64 products + 4-step butterfly. Numerics match the
// verified path (f64 dot -> f32 round -> +b1 -> relu -> f64 second dot -> f32 +b2).
// MODE 0: first layer; MODE 1: middle; MODE 2: last.
template <int MODE>
__global__ __launch_bounds__(256) void decide_k(const float* __restrict__ x, const float* __restrict__ W1,
                                                const float* __restrict__ b1, const float* __restrict__ W2,
                                                const float* __restrict__ b2, const float* __restrict__ gum,
                                                int* __restrict__ state, int* __restrict__ act,
                                                float* __restrict__ zout, float* __restrict__ eout,
                                                float layerf) {
  __shared__ float W1s[128][65];
  __shared__ float b1s[64];
  __shared__ float w2s[128];
  __shared__ float b2s[2];
  __shared__ float xs[4][16][132];
  int t = threadIdx.x;
  for (int e = t; e < 8192; e += 256) W1s[e >> 6][e & 63] = W1[e];
  if (t < 64) b1s[t] = b1[t];
  if (t < 128) w2s[t] = W2[t];
  if (t < 2) b2s[t] = b2[t];

  int lane = t & 63, w = t >> 6;
  int n0 = blockIdx.x * 64 + w * 16;
  // stage 16 x-rows into xs[w][16][132] (float4-aligned: 132*4B row stride)
#pragma unroll
  for (int i = 0; i < 8; ++i) {
    int f = lane + 64 * i;
    int row = f >> 5, c4 = f & 31;
    int gr = n0 + row;
    float4 v = make_float4(0.f, 0.f, 0.f, 0.f);
    if (gr < NN) v = ((const float4*)x)[(size_t)gr * 32 + c4];
    *(float4*)&xs[w][row][4 * c4] = v;
  }
  __syncthreads();

  int g = lane >> 4, r = lane & 15;
  bool writer = (r < 4);
  int mynode = n0 + 4 * g + r;  // meaningful only for writer lanes
  int st = 0;
  if (MODE > 0 && writer && mynode < NN) st = state[mynode];
  bool m_act = writer && (mynode < NN) && (MODE == 0 || st == 0);
  unsigned long long actmask = __ballot(m_act);
  if (MODE > 0 && actmask == 0ULL) return;  // wave-uniform skip

  d4 acc0 = {0., 0., 0., 0.}, acc1 = {0., 0., 0., 0.};
  d4 acc2 = {0., 0., 0., 0.}, acc3 = {0., 0., 0., 0.};
#pragma unroll 4
  for (int ks = 0; ks < 32; ++ks) {
    int k = 4 * ks + g;
    double av = (double)xs[w][r][k];      // A[row=r][k]
    double b0 = (double)W1s[k][r];        // B[k][col], N-tile 0
    double b1v = (double)W1s[k][16 + r];  // N-tile 1
    double b2v = (double)W1s[k][32 + r];  // N-tile 2
    double b3v = (double)W1s[k][48 + r];  // N-tile 3
    acc0 = __builtin_amdgcn_mfma_f64_16x16x4f64(av, b0, acc0, 0, 0, 0);
    acc1 = __builtin_amdgcn_mfma_f64_16x16x4f64(av, b1v, acc1, 0, 0, 0);
    acc2 = __builtin_amdgcn_mfma_f64_16x16x4f64(av, b2v, acc2, 0, 0, 0);
    acc3 = __builtin_amdgcn_mfma_f64_16x16x4f64(av, b3v, acc3, 0, 0, 0);
  }

  // D layout: row = 4*g + i, hidden unit j = ntile*16 + r
  double p0[4], p1[4];
#pragma unroll
  for (int i = 0; i < 4; ++i) {
    float h0 = fmaxf((float)acc0[i] + b1s[r], 0.f);
    float h1 = fmaxf((float)acc1[i] + b1s[16 + r], 0.f);
    float h2 = fmaxf((float)acc2[i] + b1s[32 + r], 0.f);
    float h3 = fmaxf((float)acc3[i] + b1s[48 + r], 0.f);
    double q0 = (double)h0 * (double)w2s[2 * r] + (double)h1 * (double)w2s[2 * (16 + r)] +
                (double)h2 * (double)w2s[2 * (32 + r)] + (double)h3 * (double)w2s[2 * (48 + r)];
    double q1 = (double)h0 * (double)w2s[2 * r + 1] + (double)h1 * (double)w2s[2 * (16 + r) + 1] +
                (double)h2 * (double)w2s[2 * (32 + r) + 1] + (double)h3 * (double)w2s[2 * (48 + r) + 1];
#pragma unroll
    for (int off = 1; off <= 8; off <<= 1) {
      q0 += __shfl_xor(q0, off);
      q1 += __shfl_xor(q1, off);
    }
    p0[i] = q0; p1[i] = q1;
  }

  // writer lane r uses row i = r
  double q0sel = p0[0], q1sel = p1[0];
  if (r == 1) { q0sel = p0[1]; q1sel = p1[1]; }
  if (r == 2) { q0sel = p0[2]; q1sel = p1[2]; }
  if (r == 3) { q0sel = p0[3]; q1sel = p1[3]; }
  bool myex = false;
  if (writer && mynode < NN) {
    float gg0 = gum[2 * (size_t)mynode];
    float gg1 = gum[2 * (size_t)mynode + 1];
    float l0 = (float)q0sel + b2s[0];
    float l1 = (float)q1sel + b2s[1];
    myex = (l1 + gg1) > (l0 + gg0);
  }
  unsigned long long exmask = __ballot(myex);

  if (m_act) {
    if (MODE == 2) {
      eout[mynode] = myex ? layerf : 3.0f;
    } else if (myex) {
      eout[mynode] = layerf;
      state[mynode] = 1;
    }
  }
  if (MODE != 2) {
    int c = __popcll(actmask & ~exmask);
    if (lane == 0 && c) atomicAdd(act, c);
  }

  // z rows for exiting (or MODE2 active) nodes
#pragma unroll
  for (int i = 0; i < 16; ++i) {
    int bitpos = 16 * (i >> 2) + (i & 3);
    bool a = (actmask >> bitpos) & 1ULL;
    bool e = (exmask >> bitpos) & 1ULL;
    if (a && (MODE == 2 || e)) {
      int node = n0 + i;
      float2 v;
      v.x = xs[w][i][2 * lane];
      v.y = xs[w][i][2 * lane + 1];
      *(float2*)&zout[(size_t)node * CH + 2 * lane] = v;
    }
  }
}

__global__ void fin_k(const int* __restrict__ act, float* __restrict__ o) {
  if (threadIdx.x == 0 && blockIdx.x == 0) {
    o[0] = 50000.0f;
    o[1] = (float)act[0];
    o[2] = (float)act[1];
  }
}

// ---------------- host ----------------
extern "C" void kernel_launch(void* const* d_in, const int* in_sizes, int n_in,
                              void* d_out, int out_size, void* d_ws, size_t ws_size,
                              hipStream_t stream) {
  const float* x_in = (const float*)d_in[0];
  const int* eidx = (const int*)d_in[1];
  const int* esrc = eidx;
  const int* edst = eidx + NE;
  const float* convw[3] = {(const float*)d_in[2], (const float*)d_in[4], (const float*)d_in[6]};
  const float* convb[3] = {(const float*)d_in[3], (const float*)d_in[5], (const float*)d_in[7]};
  const float* cw1 = (const float*)d_in[8];
  const float* cb1 = (const float*)d_in[9];
  const float* cw2 = (const float*)d_in[10];
  const float* cb2 = (const float*)d_in[11];
  // d_in[12] = temp_w: unused (temperature > 0 cancels in the argmax)

  float* out = (float*)d_out;
  float* zout = out;
  float* eout = out + (size_t)NN * CH;
  float* aout = eout + NN;

  char* w = (char*)d_ws;
  float* P = (float*)w;   w += (size_t)NN * CH * 4;
  float* Q = (float*)w;   w += (size_t)NN * CH * 4;
  int* eids = (int*)w;    w += (size_t)NE * 4;      // becomes srcs in-place after gath_k
  float* norms = (float*)w; w += (size_t)NE * 4;
  float* gum = (float*)w; w += (size_t)3 * NN * 2 * 4;
  int* offs = (int*)w;    w += (size_t)(NN + 1) * 4;
  float* dinv = (float*)w; w += (size_t)NN * 4;
  char* zr0 = w;
  int* degi = (int*)w;    w += (size_t)NN * 4;
  int* cnt = (int*)w;     w += (size_t)NN * 4;
  int* state = (int*)w;   w += (size_t)NN * 4;
  int* act = (int*)w;     w += 64;
  int* parts = (int*)w;   w += 1024;

  hipMemsetAsync(zr0, 0, (size_t)(3 * NN) * 4 + 64, stream);

  uint32_t key[3][2];
  for (int l = 0; l < 3; ++l) {
    uint32_t a = 0u, b = (uint32_t)l;
    tf2x32(0u, 42u, a, b);
    key[l][0] = a; key[l][1] = b;
  }

  const int nblkN = (NN + 255) / 256;
  deg_k<<<(NE + 255) / 256, 256, 0, stream>>>(edst, degi);
  dinv_k<<<nblkN, 256, 0, stream>>>(degi, dinv);
  scan1_k<<<nblkN, 256, 0, stream>>>(degi, offs, parts);
  scan2_k<<<1, 64, 0, stream>>>(parts, nblkN);
  scan3_k<<<nblkN, 256, 0, stream>>>(offs, parts);
  place_k<<<(NE + 255) / 256, 256, 0, stream>>>(edst, offs, cnt, eids);
  sort_k<<<nblkN, 256, 0, stream>>>(offs, eids);
  gath_k<<<(NE + 255) / 256, 256, 0, stream>>>(eids, esrc, edst, dinv, eids, norms);
  gum_k<<<(3 * NN + 255) / 256, 256, 0, stream>>>(gum, key[0][0], key[0][1], key[1][0], key[1][1],
                                                  key[2][0], key[2][1]);

  const int DB = (NN + 63) / 64;  // 782 blocks, 64 nodes each
  for (int l = 0; l < 3; ++l) {
    const float* xin = (l == 0) ? x_in : Q;
    lin_k<<<(NN + 31) / 32, 256, 0, stream>>>(xin, convw[l], P);
    agg_k<<<NN / 4, 256, 0, stream>>>(P, dinv, offs, eids, norms, convb[l], Q, (l < 2) ? 1 : 0);
    if (l == 0)
      decide_k<0><<<DB, 256, 0, stream>>>(Q, cw1, cb1, cw2, cb2, gum, state, act + 0, zout, eout, 0.0f);
    else if (l == 1)
      decide_k<1><<<DB, 256, 0, stream>>>(Q, cw1, cb1, cw2, cb2, gum + (size_t)NN * 2, state, act + 1,
                                          zout, eout, 1.0f);
    else
      decide_k<2><<<DB, 256, 0, stream>>>(Q, cw1, cb1, cw2, cb2, gum + (size_t)2 * NN * 2, state, act,
                                          zout, eout, 2.0f);
  }
  fin_k<<<1, 64, 0, stream>>>(act, aout);
}